// Round 16
// baseline (38.158 us; speedup 1.0000x reference)
//
#include <hip/hip_runtime.h>

#define BB    256
#define NN    128
#define AA    15
#define HH    32
#define MIDD  256
#define NCRIT 16                 // critic blocks (blk 0..15)
#define NMSG  (2 * BB)           // 512 messenger half-blocks
#define CTRF  8192               // float offset of counter in ws (byte 32768)

typedef _Float16 h2_t  __attribute__((ext_vector_type(2)));
typedef _Float16 f16x8 __attribute__((ext_vector_type(8)));
typedef float    f32x4 __attribute__((ext_vector_type(4)));

struct MsgS {
    _Float16 vh[NN][HH];        // 8 KB  f16 v (all 128 j)
    float4   p4[8][64];         // 8 KB  chunk-major p for this half's 64 rows
    float    part[8][8][8];     // 2 KB  [jg][rg][rr]
};
struct CriS {
    _Float16 hA[2][16][264];    // 16.9 KB padded activation ping-pong
};

// aux layout: [0:128) mw1 | [128:224) aw1(rows0-2) | [224:256) ab1
//             [256:288) aw2 | [288:320) mw2 | [320:352) mb1 | [352] mb2 | [353] ab2
__global__ __launch_bounds__(512, 4) void gacq_v16(
    const float* __restrict__ obs,
    const float* __restrict__ mw1, const float* __restrict__ mb1,
    const float* __restrict__ mw2, const float* __restrict__ mb2,
    const float* __restrict__ aw1, const float* __restrict__ ab1,
    const float* __restrict__ aw2, const float* __restrict__ ab2,
    const float* __restrict__ cw1, const float* __restrict__ cb1,
    const float* __restrict__ cw2, const float* __restrict__ cb2,
    const float* __restrict__ cw3, const float* __restrict__ cb3,
    const float* __restrict__ cw4, const float* __restrict__ cb4,
    float* __restrict__ out, float* __restrict__ wsf)
{
    __shared__ __align__(16) float aux_s[356];
    __shared__ __align__(16) float obs_s[NN];
    __shared__ __align__(16) union { MsgS m; CriS c; } u_s;
    __shared__ int last_s;

    const int blk  = blockIdx.x;
    const int t    = threadIdx.x;
    const int lane = t & 63;

    if (blk >= NCRIT) {
        // ============ messenger half-block: batch b, row-half h (64 rows) ============
        const int idx = blk - NCRIT;
        const int b   = idx >> 1;
        const int h   = idx & 1;

        if (t < NN) obs_s[t] = obs[b * NN + t];
        if (t < 354) {
            float v;
            if      (t < 128) v = mw1[t];
            else if (t < 224) v = aw1[t - 128];
            else if (t < 256) v = ab1[t - 224];
            else if (t < 288) v = aw2[t - 256];
            else if (t < 320) v = mw2[t - 288];
            else if (t < 352) v = mb1[t - 320];
            else if (t == 352) v = mb2[0];
            else               v = ab2[0];
            aux_s[t] = v;
        }
        __syncthreads();

        // v[j][k] as f16 pairs — all 128 j
        for (int e = t; e < NN * HH / 2; e += 512) {
            const int   j  = e >> 4, kp = e & 15;
            const int   k0 = kp * 2;
            const float cj = (float)j * (1.0f / (float)NN);
            const float v0 = obs_s[j] * aux_s[64 + k0]     + cj * aux_s[96 + k0]     + aux_s[320 + k0];
            const float v1 = obs_s[j] * aux_s[64 + k0 + 1] + cj * aux_s[96 + k0 + 1] + aux_s[320 + k0 + 1];
            h2_t p; p[0] = (_Float16)v0; p[1] = (_Float16)v1;
            *(h2_t*)&u_s.m.vh[j][k0] = p;
        }

        const int kg = t & 7;           // k = kg*4+kk (lane bits 0-2)
        const int rg = (t >> 3) & 7;    // 8 row-groups of 8 rows (lane bits 3-5)
        const int jg = t >> 6;          // wave = j-group: j in [jg*16, jg*16+16)

        h2_t u2[8][2], w2h[2];
        w2h[0][0] = (_Float16)aux_s[288 + kg * 4 + 0];
        w2h[0][1] = (_Float16)aux_s[288 + kg * 4 + 1];
        w2h[1][0] = (_Float16)aux_s[288 + kg * 4 + 2];
        w2h[1][1] = (_Float16)aux_s[288 + kg * 4 + 3];
#pragma unroll
        for (int rr = 0; rr < 8; ++rr) {
            const int   row = h * 64 + rg * 8 + rr;
            const float ob  = obs_s[row];
            const float cr  = (float)row * (1.0f / (float)NN);
#pragma unroll
            for (int kp = 0; kp < 2; ++kp) {
                const int k0 = kg * 4 + kp * 2;
                u2[rr][kp][0] = (_Float16)(ob * aux_s[k0]     + cr * aux_s[32 + k0]);
                u2[rr][kp][1] = (_Float16)(ob * aux_s[k0 + 1] + cr * aux_s[32 + k0 + 1]);
            }
        }
        __syncthreads();   // v ready

        // ---- stage 1: 8 rows x 4 k x 16 j, 2-deep LDS pipeline ----
        float acc[8];
#pragma unroll
        for (int rr = 0; rr < 8; ++rr) acc[rr] = 0.f;
        const int j0 = jg * 16;
        {
            const h2_t   zero  = (h2_t)((_Float16)0);
            const uint2* vbase = (const uint2*)&u_s.m.vh[0][kg * 4];   // row stride 8 uint2
            uint2 vc0 = vbase[j0 * 8];
            uint2 vc1 = vbase[(j0 + 1) * 8];
#pragma unroll 4
            for (int jj = 0; jj < 16; ++jj) {
                const int   nj = j0 + ((jj + 2) & 15);
                const uint2 vn = vbase[nj * 8];
                const h2_t  va = __builtin_bit_cast(h2_t, vc0.x);
                const h2_t  vb = __builtin_bit_cast(h2_t, vc0.y);
#pragma unroll
                for (int rr = 0; rr < 8; ++rr) {
                    h2_t s0 = u2[rr][0] + va;
                    h2_t s1 = u2[rr][1] + vb;
                    s0 = __builtin_elementwise_max(s0, zero);
                    s1 = __builtin_elementwise_max(s1, zero);
                    acc[rr] = __builtin_amdgcn_fdot2(s0, w2h[0], acc[rr], false);
                    acc[rr] = __builtin_amdgcn_fdot2(s1, w2h[1], acc[rr], false);
                }
                vc0 = vc1;
                vc1 = vn;
            }
        }
        // kg-reduce in-register (lane bits 0-2)
#pragma unroll
        for (int m = 1; m <= 4; m <<= 1)
#pragma unroll
            for (int rr = 0; rr < 8; ++rr) acc[rr] += __shfl_xor(acc[rr], m);
        if (kg == 0) {
            *(float4*)&u_s.m.part[jg][rg][0] = make_float4(acc[0], acc[1], acc[2], acc[3]);
            *(float4*)&u_s.m.part[jg][rg][4] = make_float4(acc[4], acc[5], acc[6], acc[7]);
        }
        __syncthreads();

        // ---- p-stage (merged msg-sum): thread = (local row lr = t&63, chunk c = t>>6) ----
        {
            const int lr = t & 63;
            const int c  = t >> 6;
            float mi = (float)NN * aux_s[352];
#pragma unroll
            for (int g = 0; g < 8; ++g) mi += u_s.m.part[g][lr >> 3][lr & 7];
            const int   row = h * 64 + lr;
            const float cr  = (float)row * (1.0f / (float)NN);
            const int   k0  = c * 4;
            float4 p;
            p.x = mi * aux_s[128 + k0 + 0] + cr * aux_s[160 + k0 + 0] + aux_s[224 + k0 + 0];
            p.y = mi * aux_s[128 + k0 + 1] + cr * aux_s[160 + k0 + 1] + aux_s[224 + k0 + 1];
            p.z = mi * aux_s[128 + k0 + 2] + cr * aux_s[160 + k0 + 2] + aux_s[224 + k0 + 2];
            p.w = mi * aux_s[128 + k0 + 3] + cr * aux_s[160 + k0 + 3] + aux_s[224 + k0 + 3];
            u_s.m.p4[c][lr] = p;
        }
        __syncthreads();

        // ---- stage 2 partial over this half's 64 rows ----
        {
            const int   a   = t >> 5;        // 16 groups, a=15 dummy
            const int   sub = t & 31;
            const float fa  = (float)a;
            float qa[HH];
#pragma unroll
            for (int k = 0; k < HH; ++k) qa[k] = fa * aux_s[192 + k];
            float s0 = 0.f, s1 = 0.f, s2 = 0.f, s3 = 0.f;
#pragma unroll
            for (int m = 0; m < 2; ++m) {
                const int lr = sub + 32 * m;
#pragma unroll
                for (int c = 0; c < 8; ++c) {
                    const float4 p4 = u_s.m.p4[c][lr];
                    const float4 w4 = *(const float4*)&aux_s[256 + c * 4];
                    const int    k0 = c * 4;
                    s0 += fmaxf(p4.x + qa[k0 + 0], 0.f) * w4.x;
                    s1 += fmaxf(p4.y + qa[k0 + 1], 0.f) * w4.y;
                    s2 += fmaxf(p4.z + qa[k0 + 2], 0.f) * w4.z;
                    s3 += fmaxf(p4.w + qa[k0 + 3], 0.f) * w4.w;
                }
            }
            float s = (s0 + s1) + (s2 + s3);
#pragma unroll
            for (int off = 1; off < 32; off <<= 1) s += __shfl_xor(s, off);
            if (sub == 0 && a < AA)
                __hip_atomic_store(&wsf[idx * 16 + a], s, __ATOMIC_RELAXED,
                                   __HIP_MEMORY_SCOPE_AGENT);
        }
        __syncthreads();   // all partial stores drained (vmcnt(0) at barrier)

        // ---- last-arriving block reduces the 512x15 partials ----
        if (t == 0) {
            __threadfence();
            int* ctr = (int*)&wsf[CTRF];
            const int old = __hip_atomic_fetch_add(ctr, 1, __ATOMIC_ACQ_REL,
                                                   __HIP_MEMORY_SCOPE_AGENT);
            last_s = (old == NMSG - 1) ? 1 : 0;
        }
        __syncthreads();
        if (last_s) {
            const float ab2v = (float)NN * aux_s[353];
            for (int i = t; i < BB * AA; i += 512) {
                const int bb = i / AA;
                const int aa = i - bb * AA;
                const float pa = __hip_atomic_load(&wsf[(bb * 2 + 0) * 16 + aa],
                                                   __ATOMIC_RELAXED, __HIP_MEMORY_SCOPE_AGENT);
                const float pb = __hip_atomic_load(&wsf[(bb * 2 + 1) * 16 + aa],
                                                   __ATOMIC_RELAXED, __HIP_MEMORY_SCOPE_AGENT);
                out[i] = pa + pb + ab2v;
            }
        }
    } else {
        // ===================== critic: MFMA, 16 batch elems per block =====================
        const int b0 = blk * 16;

        for (int e = t; e < 16 * NN; e += 512)
            u_s.c.hA[0][e >> 7][e & 127] = (_Float16)obs[(b0 + (e >> 7)) * NN + (e & 127)];
        __syncthreads();

        const int w    = t >> 6;
        const int arow = lane & 15;         // A row / B col / D col selector
        const int koff = (lane >> 4) * 8;   // contiguous k start within K=32 step
        const int n0   = w * 32;            // wave: N-tiles n0, n0+16

        auto critLayer = [&](const _Float16 (&Ain)[16][264], _Float16 (&Aout)[16][264],
                             const float* __restrict__ W, const float* __restrict__ bias,
                             const int Kd) {
            f32x4 acc0 = {0.f, 0.f, 0.f, 0.f};
            f32x4 acc1 = {0.f, 0.f, 0.f, 0.f};
            for (int ks = 0; ks < Kd; ks += 32) {
                const f16x8  af = *(const f16x8*)&Ain[arow][ks + koff];
                const float* wp = W + (size_t)(ks + koff) * MIDD + n0 + arow;
                f16x8 bf0, bf1;
#pragma unroll
                for (int j = 0; j < 8; ++j) {
                    bf0[j] = (_Float16)wp[j * MIDD];
                    bf1[j] = (_Float16)wp[j * MIDD + 16];
                }
                acc0 = __builtin_amdgcn_mfma_f32_16x16x32_f16(af, bf0, acc0, 0, 0, 0);
                acc1 = __builtin_amdgcn_mfma_f32_16x16x32_f16(af, bf1, acc1, 0, 0, 0);
            }
            const float b0v = bias[n0 + arow];
            const float b1v = bias[n0 + 16 + arow];
#pragma unroll
            for (int reg = 0; reg < 4; ++reg) {
                const int i = (lane >> 4) * 4 + reg;
                Aout[i][n0 + arow]      = (_Float16)fmaxf(acc0[reg] + b0v, 0.f);
                Aout[i][n0 + 16 + arow] = (_Float16)fmaxf(acc1[reg] + b1v, 0.f);
            }
        };

        critLayer(u_s.c.hA[0], u_s.c.hA[1], cw1, cb1, 128);
        __syncthreads();
        critLayer(u_s.c.hA[1], u_s.c.hA[0], cw2, cb2, 256);
        __syncthreads();
        critLayer(u_s.c.hA[0], u_s.c.hA[1], cw3, cb3, 256);
        __syncthreads();

        // head: value_i = sum_n h3[i][n]*cw4[n] + cb4
        {
            const int i  = t >> 5;      // batch elem 0..15
            const int sl = t & 31;      // 8-wide n slice
            float s = 0.f;
#pragma unroll
            for (int j = 0; j < 8; ++j)
                s += (float)u_s.c.hA[1][i][sl * 8 + j] * cw4[sl * 8 + j];
#pragma unroll
            for (int off = 1; off < 32; off <<= 1) s += __shfl_xor(s, off);
            if (sl == 0) out[BB * AA + b0 + i] = s + cb4[0];
        }
    }
}

extern "C" void kernel_launch(void* const* d_in, const int* in_sizes, int n_in,
                              void* d_out, int out_size, void* d_ws, size_t ws_size,
                              hipStream_t stream) {
    const float* obs = (const float*)d_in[0];
    const float* mw1 = (const float*)d_in[1];
    const float* mb1 = (const float*)d_in[2];
    const float* mw2 = (const float*)d_in[3];
    const float* mb2 = (const float*)d_in[4];
    const float* aw1 = (const float*)d_in[5];
    const float* ab1 = (const float*)d_in[6];
    const float* aw2 = (const float*)d_in[7];
    const float* ab2 = (const float*)d_in[8];
    const float* cw1 = (const float*)d_in[9];
    const float* cb1 = (const float*)d_in[10];
    const float* cw2 = (const float*)d_in[11];
    const float* cb2 = (const float*)d_in[12];
    const float* cw3 = (const float*)d_in[13];
    const float* cb3 = (const float*)d_in[14];
    const float* cw4 = (const float*)d_in[15];
    const float* cb4 = (const float*)d_in[16];
    float* out = (float*)d_out;
    float* wsf = (float*)d_ws;

    // zero the completion counter each call (graph-capturable memset node)
    hipMemsetAsync((char*)d_ws + CTRF * sizeof(float), 0, sizeof(int), stream);

    gacq_v16<<<dim3(NCRIT + NMSG), dim3(512), 0, stream>>>(
        obs, mw1, mb1, mw2, mb2, aw1, ab1, aw2, ab2,
        cw1, cb1, cw2, cb2, cw3, cb3, cw4, cb4, out, wsf);
}

// Round 17
// 17.230 us; speedup vs baseline: 2.2147x; 2.2147x over previous
//
#include <hip/hip_runtime.h>

#define BB    256
#define NN    128
#define AA    15
#define HH    32
#define MIDD  256
#define NCRIT 64    // critic blocks, 4 batch elems each

typedef _Float16 h2_t  __attribute__((ext_vector_type(2)));
typedef _Float16 f16x8 __attribute__((ext_vector_type(8)));
typedef float    f32x4 __attribute__((ext_vector_type(4)));

struct MsgS {
    _Float16 vh[NN][HH];        // 8 KB  f16 v
    float4   p4[8][NN];         // 16 KB chunk-major p (conflict-free)
    float    part[4][16][8];    // 2 KB  jg-partials
};
struct CriS {
    _Float16 hA[2][16][264];    // 16.9 KB padded activation ping-pong (rows 0-3 live)
};

// aux layout: [0:128) mw1 | [128:224) aw1(rows0-2) | [224:256) ab1
//             [256:288) aw2 | [288:320) mw2 | [320:352) mb1 | [352] mb2 | [353] ab2
__global__ __launch_bounds__(512, 4) void gacq_v17(
    const float* __restrict__ obs,
    const float* __restrict__ mw1, const float* __restrict__ mb1,
    const float* __restrict__ mw2, const float* __restrict__ mb2,
    const float* __restrict__ aw1, const float* __restrict__ ab1,
    const float* __restrict__ aw2, const float* __restrict__ ab2,
    const float* __restrict__ cw1, const float* __restrict__ cb1,
    const float* __restrict__ cw2, const float* __restrict__ cb2,
    const float* __restrict__ cw3, const float* __restrict__ cb3,
    const float* __restrict__ cw4, const float* __restrict__ cb4,
    float* __restrict__ out)
{
    __shared__ __align__(16) float aux_s[356];
    __shared__ __align__(16) float obs_s[NN];
    __shared__ __align__(16) union { MsgS m; CriS c; } u_s;

    const int blk  = blockIdx.x;
    const int t    = threadIdx.x;
    const int lane = t & 63;

    if (blk >= NCRIT) {
        // ===================== messenger + actor (one b per block) — v13 verbatim =====================
        const int b = blk - NCRIT;

        if (t < NN) obs_s[t] = obs[b * NN + t];
        if (t < 354) {
            float v;
            if      (t < 128) v = mw1[t];
            else if (t < 224) v = aw1[t - 128];
            else if (t < 256) v = ab1[t - 224];
            else if (t < 288) v = aw2[t - 256];
            else if (t < 320) v = mw2[t - 288];
            else if (t < 352) v = mb1[t - 320];
            else if (t == 352) v = mb2[0];
            else               v = ab2[0];
            aux_s[t] = v;
        }
        __syncthreads();

        // v[j][k] as f16 pairs
        for (int e = t; e < NN * HH / 2; e += 512) {
            const int   j  = e >> 4, kp = e & 15;
            const int   k0 = kp * 2;
            const float cj = (float)j * (1.0f / (float)NN);
            const float v0 = obs_s[j] * aux_s[64 + k0]     + cj * aux_s[96 + k0]     + aux_s[320 + k0];
            const float v1 = obs_s[j] * aux_s[64 + k0 + 1] + cj * aux_s[96 + k0 + 1] + aux_s[320 + k0 + 1];
            h2_t p; p[0] = (_Float16)v0; p[1] = (_Float16)v1;
            *(h2_t*)&u_s.m.vh[j][k0] = p;
        }

        const int kg = t & 7;           // k = kg*4 + kk  (lane bits 0-2)
        const int rg = (t >> 3) & 15;   // rows rg*8 + rr
        const int jg = t >> 7;          // j in [jg*32, jg*32+32)

        h2_t u2[8][2], w2h[2];
        w2h[0][0] = (_Float16)aux_s[288 + kg * 4 + 0];
        w2h[0][1] = (_Float16)aux_s[288 + kg * 4 + 1];
        w2h[1][0] = (_Float16)aux_s[288 + kg * 4 + 2];
        w2h[1][1] = (_Float16)aux_s[288 + kg * 4 + 3];
#pragma unroll
        for (int rr = 0; rr < 8; ++rr) {
            const int   row = rg * 8 + rr;
            const float ob  = obs_s[row];
            const float cr  = (float)row * (1.0f / (float)NN);
#pragma unroll
            for (int kp = 0; kp < 2; ++kp) {
                const int k0 = kg * 4 + kp * 2;
                u2[rr][kp][0] = (_Float16)(ob * aux_s[k0]     + cr * aux_s[32 + k0]);
                u2[rr][kp][1] = (_Float16)(ob * aux_s[k0 + 1] + cr * aux_s[32 + k0 + 1]);
            }
        }
        __syncthreads();   // v ready

        // ---- stage 1: 8 rows x 4 k x 32 j, 2-deep LDS software pipeline ----
        float acc[8];
#pragma unroll
        for (int rr = 0; rr < 8; ++rr) acc[rr] = 0.f;
        const int j0 = jg * 32;
        {
            const h2_t   zero  = (h2_t)((_Float16)0);
            const uint2* vbase = (const uint2*)&u_s.m.vh[0][kg * 4];   // row stride 8 uint2
            uint2 vc0 = vbase[j0 * 8];
            uint2 vc1 = vbase[(j0 + 1) * 8];
#pragma unroll 4
            for (int jj = 0; jj < 32; ++jj) {
                const int   nj = j0 + ((jj + 2) & 31);
                const uint2 vn = vbase[nj * 8];
                const h2_t  va = __builtin_bit_cast(h2_t, vc0.x);
                const h2_t  vb = __builtin_bit_cast(h2_t, vc0.y);
#pragma unroll
                for (int rr = 0; rr < 8; ++rr) {
                    h2_t s0 = u2[rr][0] + va;
                    h2_t s1 = u2[rr][1] + vb;
                    s0 = __builtin_elementwise_max(s0, zero);
                    s1 = __builtin_elementwise_max(s1, zero);
                    acc[rr] = __builtin_amdgcn_fdot2(s0, w2h[0], acc[rr], false);
                    acc[rr] = __builtin_amdgcn_fdot2(s1, w2h[1], acc[rr], false);
                }
                vc0 = vc1;
                vc1 = vn;
            }
        }
        // kg-reduce in-register (lane bits 0-2)
#pragma unroll
        for (int m = 1; m <= 4; m <<= 1)
#pragma unroll
            for (int rr = 0; rr < 8; ++rr) acc[rr] += __shfl_xor(acc[rr], m);
        if (kg == 0) {
            *(float4*)&u_s.m.part[jg][rg][0] = make_float4(acc[0], acc[1], acc[2], acc[3]);
            *(float4*)&u_s.m.part[jg][rg][4] = make_float4(acc[4], acc[5], acc[6], acc[7]);
        }
        __syncthreads();

        // ---- p-stage (merged msg-sum): thread (row = t&127, chunks t>>7 and +4) ----
        {
            const int row = t & 127;
            float mi = (float)NN * aux_s[352];
#pragma unroll
            for (int g = 0; g < 4; ++g) mi += u_s.m.part[g][row >> 3][row & 7];
            const float cr = (float)row * (1.0f / (float)NN);
#pragma unroll
            for (int it = 0; it < 2; ++it) {
                const int c  = (t >> 7) + it * 4;
                const int k0 = c * 4;
                float4 p;
                p.x = mi * aux_s[128 + k0 + 0] + cr * aux_s[160 + k0 + 0] + aux_s[224 + k0 + 0];
                p.y = mi * aux_s[128 + k0 + 1] + cr * aux_s[160 + k0 + 1] + aux_s[224 + k0 + 1];
                p.z = mi * aux_s[128 + k0 + 2] + cr * aux_s[160 + k0 + 2] + aux_s[224 + k0 + 2];
                p.w = mi * aux_s[128 + k0 + 3] + cr * aux_s[160 + k0 + 3] + aux_s[224 + k0 + 3];
                u_s.m.p4[c][row] = p;
            }
        }
        __syncthreads();

        // ---- stage 2: a = t>>5 (16 groups, a=15 dummy), sub = t&31, rows sub+32m ----
        {
            const int   a   = t >> 5;
            const int   sub = t & 31;
            const float fa  = (float)a;
            float qa[HH];
#pragma unroll
            for (int k = 0; k < HH; ++k) qa[k] = fa * aux_s[192 + k];
            float s0 = 0.f, s1 = 0.f, s2 = 0.f, s3 = 0.f;
#pragma unroll
            for (int m = 0; m < 4; ++m) {
                const int row = sub + 32 * m;
#pragma unroll
                for (int c = 0; c < 8; ++c) {
                    const float4 p4 = u_s.m.p4[c][row];
                    const float4 w4 = *(const float4*)&aux_s[256 + c * 4];
                    const int    k0 = c * 4;
                    s0 += fmaxf(p4.x + qa[k0 + 0], 0.f) * w4.x;
                    s1 += fmaxf(p4.y + qa[k0 + 1], 0.f) * w4.y;
                    s2 += fmaxf(p4.z + qa[k0 + 2], 0.f) * w4.z;
                    s3 += fmaxf(p4.w + qa[k0 + 3], 0.f) * w4.w;
                }
            }
            float s = (s0 + s1) + (s2 + s3);
#pragma unroll
            for (int off = 1; off < 32; off <<= 1) s += __shfl_xor(s, off);
            if (sub == 0 && a < AA)
                out[b * AA + a] = s + (float)NN * aux_s[353];
        }
    } else {
        // ===== critic: MFMA, 4 batch elems per block, 64 blocks (parallel cold-weight fetch) =====
        const int b0 = blk * 4;

        // obs -> hA rows 0-3; rows 4-15 zeroed (row-independence keeps them inert)
        for (int e = t; e < 16 * NN; e += 512) {
            const int row = e >> 7;
            u_s.c.hA[0][row][e & 127] =
                (row < 4) ? (_Float16)obs[(b0 + row) * NN + (e & 127)] : (_Float16)0.f;
        }
        __syncthreads();

        const int w    = t >> 6;
        const int arow = lane & 15;         // A row / B col / D col selector
        const int koff = (lane >> 4) * 8;   // contiguous k start within K=32 step
        const int n0   = w * 32;            // wave: N-tiles n0, n0+16

        auto critLayer = [&](const _Float16 (&Ain)[16][264], _Float16 (&Aout)[16][264],
                             const float* __restrict__ W, const float* __restrict__ bias,
                             const int Kd) {
            f32x4 acc0 = {0.f, 0.f, 0.f, 0.f};
            f32x4 acc1 = {0.f, 0.f, 0.f, 0.f};
            for (int ks = 0; ks < Kd; ks += 32) {
                const f16x8  af = *(const f16x8*)&Ain[arow][ks + koff];
                const float* wp = W + (size_t)(ks + koff) * MIDD + n0 + arow;
                f16x8 bf0, bf1;
#pragma unroll
                for (int j = 0; j < 8; ++j) {
                    bf0[j] = (_Float16)wp[j * MIDD];
                    bf1[j] = (_Float16)wp[j * MIDD + 16];
                }
                acc0 = __builtin_amdgcn_mfma_f32_16x16x32_f16(af, bf0, acc0, 0, 0, 0);
                acc1 = __builtin_amdgcn_mfma_f32_16x16x32_f16(af, bf1, acc1, 0, 0, 0);
            }
            const float b0v = bias[n0 + arow];
            const float b1v = bias[n0 + 16 + arow];
#pragma unroll
            for (int reg = 0; reg < 4; ++reg) {
                const int i = (lane >> 4) * 4 + reg;
                Aout[i][n0 + arow]      = (_Float16)fmaxf(acc0[reg] + b0v, 0.f);
                Aout[i][n0 + 16 + arow] = (_Float16)fmaxf(acc1[reg] + b1v, 0.f);
            }
        };

        critLayer(u_s.c.hA[0], u_s.c.hA[1], cw1, cb1, 128);
        __syncthreads();
        critLayer(u_s.c.hA[1], u_s.c.hA[0], cw2, cb2, 256);
        __syncthreads();
        critLayer(u_s.c.hA[0], u_s.c.hA[1], cw3, cb3, 256);
        __syncthreads();

        // head: value_i = sum_n h3[i][n]*cw4[n] + cb4   (groups 0-3 live)
        {
            const int i  = t >> 5;      // batch slot 0..15 (only 0..3 valid)
            const int sl = t & 31;      // 8-wide n slice
            float s = 0.f;
#pragma unroll
            for (int j = 0; j < 8; ++j)
                s += (float)u_s.c.hA[1][i][sl * 8 + j] * cw4[sl * 8 + j];
#pragma unroll
            for (int off = 1; off < 32; off <<= 1) s += __shfl_xor(s, off);
            if (sl == 0 && i < 4) out[BB * AA + b0 + i] = s + cb4[0];
        }
    }
}

extern "C" void kernel_launch(void* const* d_in, const int* in_sizes, int n_in,
                              void* d_out, int out_size, void* d_ws, size_t ws_size,
                              hipStream_t stream) {
    const float* obs = (const float*)d_in[0];
    const float* mw1 = (const float*)d_in[1];
    const float* mb1 = (const float*)d_in[2];
    const float* mw2 = (const float*)d_in[3];
    const float* mb2 = (const float*)d_in[4];
    const float* aw1 = (const float*)d_in[5];
    const float* ab1 = (const float*)d_in[6];
    const float* aw2 = (const float*)d_in[7];
    const float* ab2 = (const float*)d_in[8];
    const float* cw1 = (const float*)d_in[9];
    const float* cb1 = (const float*)d_in[10];
    const float* cw2 = (const float*)d_in[11];
    const float* cb2 = (const float*)d_in[12];
    const float* cw3 = (const float*)d_in[13];
    const float* cb3 = (const float*)d_in[14];
    const float* cw4 = (const float*)d_in[15];
    const float* cb4 = (const float*)d_in[16];
    float* out = (float*)d_out;

    gacq_v17<<<dim3(BB + NCRIT), dim3(512), 0, stream>>>(
        obs, mw1, mb1, mw2, mb2, aw1, ab1, aw2, ab2,
        cw1, cb1, cw2, cb2, cw3, cb3, cw4, cb4, out);
}